// Round 4
// baseline (254.106 us; speedup 1.0000x reference)
//
#include <hip/hip_runtime.h>
#include <hip/hip_bf16.h>
#include <math.h>

#define MDIM 8192
#define NDIM 4096
#define KDIM 128

typedef __bf16 bf16x8 __attribute__((ext_vector_type(8)));
typedef float f32x4 __attribute__((ext_vector_type(4)));

__device__ __forceinline__ unsigned short f32_to_bf16_rne(float f) {
  unsigned int u = __float_as_uint(f);
  u += 0x7fffu + ((u >> 16) & 1u);
  return (unsigned short)(u >> 16);
}

// Convert f32 -> bf16 (vectorized), and compute sum of squares (for ||U||_F, ||V||_F)
__global__ void convert_kernel(const float* __restrict__ X, unsigned short* __restrict__ Xb,
                               double* __restrict__ partial, int n4) {
  int tid = blockIdx.x * blockDim.x + threadIdx.x;
  int stride = gridDim.x * blockDim.x;
  float s = 0.f;
  const float4* X4 = (const float4*)X;
  ushort4* Xb4 = (ushort4*)Xb;
  for (int i = tid; i < n4; i += stride) {
    float4 v = X4[i];
    s += v.x * v.x + v.y * v.y + v.z * v.z + v.w * v.w;
    ushort4 p;
    p.x = f32_to_bf16_rne(v.x);
    p.y = f32_to_bf16_rne(v.y);
    p.z = f32_to_bf16_rne(v.z);
    p.w = f32_to_bf16_rne(v.w);
    Xb4[i] = p;
  }
  for (int off = 32; off > 0; off >>= 1) s += __shfl_down(s, off, 64);
  __shared__ float sw[4];
  int lane = threadIdx.x & 63, wid = threadIdx.x >> 6;
  if (lane == 0) sw[wid] = s;
  __syncthreads();
  if (threadIdx.x == 0) partial[blockIdx.x] = (double)(sw[0] + sw[1] + sw[2] + sw[3]);
}

// Fused sum((Xb*Yb^T - T)^2) over one 128x128 tile per block.
// 256 thr = 4 waves (2x2), each wave a 64x64 sub-tile.
// Operand-swapped MFMA: acc[p][q] = mfma(yfrag[p], xfrag[q]) computes P^T
// fragments, so each lane's f32x4 holds P[row][4 consecutive cols] and the
// T comparison is one float4 load per MFMA tile (1KB/wave-instr).
// T is loaded NON-TEMPORALLY (nt bit): the 448MB read-once stream must not
// evict the 3MB of U/V panels from L2/LLC — panel re-reads across blocks are
// the difference between 896MB and 451MB of HBM traffic.
// Natural row-major 2D raster: consecutive blocks share the same 2 block-rows,
// X panels (64KB) stay hot, Y panel row (<=2MB) fits each XCD L2.
__global__ __launch_bounds__(256) void fused_tile(
    const unsigned short* __restrict__ Xb,  // [prows][128] bf16 bits
    const unsigned short* __restrict__ Yb,  // [pcols][128] bf16 bits
    const float* __restrict__ T,            // [prows][pcols]
    double* __restrict__ partial,
    int ldT) {
  const int tid = threadIdx.x;
  const int lane = tid & 63;
  const int wid = tid >> 6;
  const int wr = wid >> 1, wc = wid & 1;
  const int l15 = lane & 15;
  const int lg = lane >> 4;  // 0..3

  const int prow0 = blockIdx.y * 128 + wr * 64;  // wave's first P-row
  const int pcol0 = blockIdx.x * 128 + wc * 64;  // wave's first P-col

  const unsigned short* Xrow = Xb + (size_t)(prow0 + l15) * KDIM + lg * 8;
  const unsigned short* Yrow = Yb + (size_t)(pcol0 + l15) * KDIM + lg * 8;

  f32x4 acc[4][4] = {};  // [p: P-col tile][q: P-row tile]
#pragma unroll
  for (int kk = 0; kk < 4; ++kk) {
    bf16x8 y[4], x[4];
#pragma unroll
    for (int p = 0; p < 4; ++p)
      y[p] = *(const bf16x8*)(Yrow + (size_t)p * 16 * KDIM + kk * 32);
#pragma unroll
    for (int q = 0; q < 4; ++q)
      x[q] = *(const bf16x8*)(Xrow + (size_t)q * 16 * KDIM + kk * 32);
#pragma unroll
    for (int p = 0; p < 4; ++p)
#pragma unroll
      for (int q = 0; q < 4; ++q)
        acc[p][q] = __builtin_amdgcn_mfma_f32_16x16x32_bf16(y[p], x[q], acc[p][q], 0, 0, 0);
  }

  // Epilogue: lane holds P[prow0+q*16+l15][pcol0+p*16+lg*4 .. +3] in acc[p][q]
  const f32x4* T4 = (const f32x4*)T;
  const int ldT4 = ldT >> 2;
  float s = 0.f;
#pragma unroll
  for (int q = 0; q < 4; ++q) {
    const size_t rbase = (size_t)(prow0 + q * 16 + l15) * ldT4;
#pragma unroll
    for (int p = 0; p < 4; ++p) {
      const f32x4 tv = __builtin_nontemporal_load(&T4[rbase + ((pcol0 + p * 16) >> 2) + lg]);
      const f32x4 av = acc[p][q];
      const float dx = av[0] - tv[0];
      const float dy = av[1] - tv[1];
      const float dz = av[2] - tv[2];
      const float dw = av[3] - tv[3];
      s += dx * dx + dy * dy + dz * dz + dw * dw;
    }
  }

  // deterministic block reduction
  for (int off = 32; off > 0; off >>= 1) s += __shfl_down(s, off, 64);
  __shared__ float swred[4];
  if (lane == 0) swred[wid] = s;
  __syncthreads();
  if (tid == 0)
    partial[blockIdx.y * gridDim.x + blockIdx.x] =
        (double)(swred[0] + swred[1] + swred[2] + swred[3]);
}

// Deterministic final reduction of all partial arrays + scalar combine.
__global__ void finalize_kernel(const double* __restrict__ pr, int nr,
                                const double* __restrict__ psm, int nsm,
                                const double* __restrict__ psd, int nsd,
                                const double* __restrict__ pu, int nu,
                                const double* __restrict__ pv, int nv,
                                float* __restrict__ out) {
  __shared__ double sh[256];
  double sums[5];
  const double* ps[5] = {pr, psm, psd, pu, pv};
  int ns[5] = {nr, nsm, nsd, nu, nv};
  for (int q = 0; q < 5; ++q) {
    double s = 0.0;
    for (int i = threadIdx.x; i < ns[q]; i += 256) s += ps[q][i];
    sh[threadIdx.x] = s;
    __syncthreads();
    for (int k = 128; k > 0; k >>= 1) {
      if (threadIdx.x < k) sh[threadIdx.x] += sh[threadIdx.x + k];
      __syncthreads();
    }
    sums[q] = sh[0];
    __syncthreads();
  }
  if (threadIdx.x == 0) {
    double recon = sums[0] / ((double)MDIM * (double)NDIM);
    double res = recon + 0.01 * (sqrt(sums[3]) + sqrt(sums[4]) + sqrt(sums[1]) + sqrt(sums[2]));
    out[0] = (float)res;
  }
}

extern "C" void kernel_launch(void* const* d_in, const int* in_sizes, int n_in,
                              void* d_out, int out_size, void* d_ws, size_t ws_size,
                              hipStream_t stream) {
  const float* A   = (const float*)d_in[0];  // [M][N]
  const float* S_m = (const float*)d_in[1];  // [M][M]
  const float* S_d = (const float*)d_in[2];  // [N][N]
  const float* U   = (const float*)d_in[3];  // [M][K]
  const float* V   = (const float*)d_in[4];  // [N][K]

  char* ws = (char*)d_ws;
  unsigned short* Ub = (unsigned short*)ws;                             // 2 MB
  unsigned short* Vb = (unsigned short*)(ws + (size_t)2 * 1024 * 1024); // 1 MB
  double* pd = (double*)(ws + (size_t)3 * 1024 * 1024);
  double* p_recon = pd;             // 2048 (32x64)
  double* p_sm    = p_recon + 2048; // 4096 (64x64)
  double* p_sd    = p_sm + 4096;    // 1024 (32x32)
  double* p_u     = p_sd + 1024;    // 256
  double* p_v     = p_u + 256;      // 256

  convert_kernel<<<256, 256, 0, stream>>>(U, Ub, p_u, MDIM * KDIM / 4);
  convert_kernel<<<256, 256, 0, stream>>>(V, Vb, p_v, NDIM * KDIM / 4);

  fused_tile<<<dim3(NDIM / 128, MDIM / 128), 256, 0, stream>>>(Ub, Vb, A, p_recon, NDIM);
  fused_tile<<<dim3(MDIM / 128, MDIM / 128), 256, 0, stream>>>(Ub, Ub, S_m, p_sm, MDIM);
  fused_tile<<<dim3(NDIM / 128, NDIM / 128), 256, 0, stream>>>(Vb, Vb, S_d, p_sd, NDIM);

  finalize_kernel<<<1, 256, 0, stream>>>(p_recon, 2048, p_sm, 4096, p_sd, 1024,
                                         p_u, 256, p_v, 256, (float*)d_out);
}

// Round 5
// 220.742 us; speedup vs baseline: 1.1511x; 1.1511x over previous
//
#include <hip/hip_runtime.h>
#include <hip/hip_bf16.h>
#include <math.h>

#define MDIM 8192
#define NDIM 4096
#define KDIM 128

typedef __bf16 bf16x8 __attribute__((ext_vector_type(8)));
typedef float f32x4 __attribute__((ext_vector_type(4)));

__device__ __forceinline__ unsigned short f32_to_bf16_rne(float f) {
  unsigned int u = __float_as_uint(f);
  u += 0x7fffu + ((u >> 16) & 1u);
  return (unsigned short)(u >> 16);
}

// Convert f32 -> bf16 (vectorized), and compute sum of squares (for ||U||_F, ||V||_F)
__global__ void convert_kernel(const float* __restrict__ X, unsigned short* __restrict__ Xb,
                               double* __restrict__ partial, int n4) {
  int tid = blockIdx.x * blockDim.x + threadIdx.x;
  int stride = gridDim.x * blockDim.x;
  float s = 0.f;
  const float4* X4 = (const float4*)X;
  ushort4* Xb4 = (ushort4*)Xb;
  for (int i = tid; i < n4; i += stride) {
    float4 v = X4[i];
    s += v.x * v.x + v.y * v.y + v.z * v.z + v.w * v.w;
    ushort4 p;
    p.x = f32_to_bf16_rne(v.x);
    p.y = f32_to_bf16_rne(v.y);
    p.z = f32_to_bf16_rne(v.z);
    p.w = f32_to_bf16_rne(v.w);
    Xb4[i] = p;
  }
  for (int off = 32; off > 0; off >>= 1) s += __shfl_down(s, off, 64);
  __shared__ float sw[4];
  int lane = threadIdx.x & 63, wid = threadIdx.x >> 6;
  if (lane == 0) sw[wid] = s;
  __syncthreads();
  if (threadIdx.x == 0) partial[blockIdx.x] = (double)(sw[0] + sw[1] + sw[2] + sw[3]);
}

// ALL THREE fused products in one dispatch (one 128x128 tile per block):
//   g in [0,2048):      sum((Ub Vb^T - A  )^2)   32 block-cols, ldT=4096
//   g in [2048,6144):   sum((Ub Ub^T - S_m)^2)   64 block-cols, ldT=8192
//   g in [6144,7168):   sum((Vb Vb^T - S_d)^2)   32 block-cols, ldT=4096
// 256 thr = 4 waves (2x2), each wave a 64x64 sub-tile.
// Operand-swapped MFMA: acc[p][q] = mfma(yfrag[p], xfrag[q]) computes P^T
// fragments, so each lane's f32x4 holds P[row][4 consecutive cols] and the
// T comparison is one float4 load per MFMA tile. Natural row-major raster
// per product (R1-proven: X panels stay hot, Y panel row fits XCD L2).
// NO non-temporal hints: the 64B access granule needs L2 to complete lines.
__global__ __launch_bounds__(256) void fused_all(
    const unsigned short* __restrict__ Ub,  // [M][128] bf16 bits
    const unsigned short* __restrict__ Vb,  // [N][128] bf16 bits
    const float* __restrict__ A,            // [M][N]
    const float* __restrict__ S_m,          // [M][M]
    const float* __restrict__ S_d,          // [N][N]
    double* __restrict__ partial) {
  const int g = blockIdx.x;

  const unsigned short* Xb;
  const unsigned short* Yb;
  const float* T;
  int ldT, v, gc;
  if (g < 2048) {
    Xb = Ub; Yb = Vb; T = A; ldT = NDIM; v = g; gc = 32;
  } else if (g < 6144) {
    Xb = Ub; Yb = Ub; T = S_m; ldT = MDIM; v = g - 2048; gc = 64;
  } else {
    Xb = Vb; Yb = Vb; T = S_d; ldT = NDIM; v = g - 6144; gc = 32;
  }
  const int r_blk = v / gc;
  const int c_blk = v - r_blk * gc;

  const int tid = threadIdx.x;
  const int lane = tid & 63;
  const int wid = tid >> 6;
  const int wr = wid >> 1, wc = wid & 1;
  const int l15 = lane & 15;
  const int lg = lane >> 4;  // 0..3

  const int prow0 = r_blk * 128 + wr * 64;  // wave's first P-row
  const int pcol0 = c_blk * 128 + wc * 64;  // wave's first P-col

  const unsigned short* Xrow = Xb + (size_t)(prow0 + l15) * KDIM + lg * 8;
  const unsigned short* Yrow = Yb + (size_t)(pcol0 + l15) * KDIM + lg * 8;

  f32x4 acc[4][4] = {};  // [p: P-col tile][q: P-row tile]
#pragma unroll
  for (int kk = 0; kk < 4; ++kk) {
    bf16x8 y[4], x[4];
#pragma unroll
    for (int p = 0; p < 4; ++p)
      y[p] = *(const bf16x8*)(Yrow + (size_t)p * 16 * KDIM + kk * 32);
#pragma unroll
    for (int q = 0; q < 4; ++q)
      x[q] = *(const bf16x8*)(Xrow + (size_t)q * 16 * KDIM + kk * 32);
#pragma unroll
    for (int p = 0; p < 4; ++p)
#pragma unroll
      for (int q = 0; q < 4; ++q)
        acc[p][q] = __builtin_amdgcn_mfma_f32_16x16x32_bf16(y[p], x[q], acc[p][q], 0, 0, 0);
  }

  // Epilogue: lane holds P[prow0+q*16+l15][pcol0+p*16+lg*4 .. +3] in acc[p][q]
  const f32x4* T4 = (const f32x4*)T;
  const int ldT4 = ldT >> 2;
  float s = 0.f;
#pragma unroll
  for (int q = 0; q < 4; ++q) {
    const size_t rbase = (size_t)(prow0 + q * 16 + l15) * ldT4;
#pragma unroll
    for (int p = 0; p < 4; ++p) {
      const f32x4 tv = T4[rbase + ((pcol0 + p * 16) >> 2) + lg];
      const f32x4 av = acc[p][q];
      const float dx = av[0] - tv[0];
      const float dy = av[1] - tv[1];
      const float dz = av[2] - tv[2];
      const float dw = av[3] - tv[3];
      s += dx * dx + dy * dy + dz * dz + dw * dw;
    }
  }

  // deterministic block reduction
  for (int off = 32; off > 0; off >>= 1) s += __shfl_down(s, off, 64);
  __shared__ float swred[4];
  if (lane == 0) swred[wid] = s;
  __syncthreads();
  if (tid == 0)
    partial[g] = (double)(swred[0] + swred[1] + swred[2] + swred[3]);
}

// Deterministic final reduction of all partial arrays + scalar combine.
__global__ void finalize_kernel(const double* __restrict__ pr, int nr,
                                const double* __restrict__ psm, int nsm,
                                const double* __restrict__ psd, int nsd,
                                const double* __restrict__ pu, int nu,
                                const double* __restrict__ pv, int nv,
                                float* __restrict__ out) {
  __shared__ double sh[256];
  double sums[5];
  const double* ps[5] = {pr, psm, psd, pu, pv};
  int ns[5] = {nr, nsm, nsd, nu, nv};
  for (int q = 0; q < 5; ++q) {
    double s = 0.0;
    for (int i = threadIdx.x; i < ns[q]; i += 256) s += ps[q][i];
    sh[threadIdx.x] = s;
    __syncthreads();
    for (int k = 128; k > 0; k >>= 1) {
      if (threadIdx.x < k) sh[threadIdx.x] += sh[threadIdx.x + k];
      __syncthreads();
    }
    sums[q] = sh[0];
    __syncthreads();
  }
  if (threadIdx.x == 0) {
    double recon = sums[0] / ((double)MDIM * (double)NDIM);
    double res = recon + 0.01 * (sqrt(sums[3]) + sqrt(sums[4]) + sqrt(sums[1]) + sqrt(sums[2]));
    out[0] = (float)res;
  }
}

extern "C" void kernel_launch(void* const* d_in, const int* in_sizes, int n_in,
                              void* d_out, int out_size, void* d_ws, size_t ws_size,
                              hipStream_t stream) {
  const float* A   = (const float*)d_in[0];  // [M][N]
  const float* S_m = (const float*)d_in[1];  // [M][M]
  const float* S_d = (const float*)d_in[2];  // [N][N]
  const float* U   = (const float*)d_in[3];  // [M][K]
  const float* V   = (const float*)d_in[4];  // [N][K]

  char* ws = (char*)d_ws;
  unsigned short* Ub = (unsigned short*)ws;                             // 2 MB
  unsigned short* Vb = (unsigned short*)(ws + (size_t)2 * 1024 * 1024); // 1 MB
  double* pd = (double*)(ws + (size_t)3 * 1024 * 1024);
  double* p_all = pd;            // 7168: [0,2048) recon | [2048,6144) S_m | [6144,7168) S_d
  double* p_u   = p_all + 7168;  // 256
  double* p_v   = p_u + 256;     // 256

  convert_kernel<<<256, 256, 0, stream>>>(U, Ub, p_u, MDIM * KDIM / 4);
  convert_kernel<<<256, 256, 0, stream>>>(V, Vb, p_v, NDIM * KDIM / 4);

  fused_all<<<7168, 256, 0, stream>>>(Ub, Vb, A, S_m, S_d, p_all);

  finalize_kernel<<<1, 256, 0, stream>>>(p_all, 2048, p_all + 2048, 4096, p_all + 6144, 1024,
                                         p_u, 256, p_v, 256, (float*)d_out);
}

// Round 6
// 185.940 us; speedup vs baseline: 1.3666x; 1.1872x over previous
//
#include <hip/hip_runtime.h>
#include <hip/hip_bf16.h>
#include <math.h>

#define MDIM 8192
#define NDIM 4096
#define KDIM 128

typedef __bf16 bf16x8 __attribute__((ext_vector_type(8)));
typedef float f32x4 __attribute__((ext_vector_type(4)));

__device__ __forceinline__ unsigned short f32_to_bf16_rne(float f) {
  unsigned int u = __float_as_uint(f);
  u += 0x7fffu + ((u >> 16) & 1u);
  return (unsigned short)(u >> 16);
}

// Convert f32 -> bf16 (vectorized), and compute sum of squares (for ||U||_F, ||V||_F)
__global__ void convert_kernel(const float* __restrict__ X, unsigned short* __restrict__ Xb,
                               double* __restrict__ partial, int n4) {
  int tid = blockIdx.x * blockDim.x + threadIdx.x;
  int stride = gridDim.x * blockDim.x;
  float s = 0.f;
  const float4* X4 = (const float4*)X;
  ushort4* Xb4 = (ushort4*)Xb;
  for (int i = tid; i < n4; i += stride) {
    float4 v = X4[i];
    s += v.x * v.x + v.y * v.y + v.z * v.z + v.w * v.w;
    ushort4 p;
    p.x = f32_to_bf16_rne(v.x);
    p.y = f32_to_bf16_rne(v.y);
    p.z = f32_to_bf16_rne(v.z);
    p.w = f32_to_bf16_rne(v.w);
    Xb4[i] = p;
  }
  for (int off = 32; off > 0; off >>= 1) s += __shfl_down(s, off, 64);
  __shared__ float sw[4];
  int lane = threadIdx.x & 63, wid = threadIdx.x >> 6;
  if (lane == 0) sw[wid] = s;
  __syncthreads();
  if (threadIdx.x == 0) partial[blockIdx.x] = (double)(sw[0] + sw[1] + sw[2] + sw[3]);
}

// ALL THREE fused products in one dispatch (one 128x128 tile per block):
//   g in [0,2048):      sum((Ub Vb^T - A  )^2)   32 block-cols, ldT=4096
//   g in [2048,6144):   sum((Ub Ub^T - S_m)^2)   64 block-cols, ldT=8192
//   g in [6144,7168):   sum((Vb Vb^T - S_d)^2)   32 block-cols, ldT=4096
// R5 counters showed latency-bound (HBM 14%, MfmaUtil 5%, VALU 7%): the
// phase-serial structure issued the 16 T loads only AFTER all MFMAs.
// Fix: PREFETCH the whole T tile into registers up front. Issue order:
// kk0 fragments -> all 16 T float4 -> sched_barrier(0). vmcnt is
// issue-in-order, so kk0 MFMAs wait only on the frags while 16KB/wave of
// T stays in flight under the MFMA phase. VGPR ~190 (launch_bounds 256,2):
// occupancy cap 8 waves/CU ~= measured 10, but in-flight bytes/CU rise
// ~50x, which is what Little's law needs at ~250ns memory latency.
__global__ __launch_bounds__(256, 2) void fused_all(
    const unsigned short* __restrict__ Ub,  // [M][128] bf16 bits
    const unsigned short* __restrict__ Vb,  // [N][128] bf16 bits
    const float* __restrict__ A,            // [M][N]
    const float* __restrict__ S_m,          // [M][M]
    const float* __restrict__ S_d,          // [N][N]
    double* __restrict__ partial) {
  const int g = blockIdx.x;

  const unsigned short* Xb;
  const unsigned short* Yb;
  const float* T;
  int ldT, v, gc;
  if (g < 2048) {
    Xb = Ub; Yb = Vb; T = A; ldT = NDIM; v = g; gc = 32;
  } else if (g < 6144) {
    Xb = Ub; Yb = Ub; T = S_m; ldT = MDIM; v = g - 2048; gc = 64;
  } else {
    Xb = Vb; Yb = Vb; T = S_d; ldT = NDIM; v = g - 6144; gc = 32;
  }
  const int r_blk = v / gc;
  const int c_blk = v - r_blk * gc;

  const int tid = threadIdx.x;
  const int lane = tid & 63;
  const int wid = tid >> 6;
  const int wr = wid >> 1, wc = wid & 1;
  const int l15 = lane & 15;
  const int lg = lane >> 4;  // 0..3

  const int prow0 = r_blk * 128 + wr * 64;  // wave's first P-row
  const int pcol0 = c_blk * 128 + wc * 64;  // wave's first P-col

  const unsigned short* Xrow = Xb + (size_t)(prow0 + l15) * KDIM + lg * 8;
  const unsigned short* Yrow = Yb + (size_t)(pcol0 + l15) * KDIM + lg * 8;

  // ---- issue kk0 fragment loads first (they gate the first MFMAs) ----
  bf16x8 y0[4], x0[4];
#pragma unroll
  for (int p = 0; p < 4; ++p)
    y0[p] = *(const bf16x8*)(Yrow + (size_t)p * 16 * KDIM);
#pragma unroll
  for (int q = 0; q < 4; ++q)
    x0[q] = *(const bf16x8*)(Xrow + (size_t)q * 16 * KDIM);

  // ---- issue ALL 16 T-tile loads now; they fly under the MFMA phase ----
  const f32x4* T4 = (const f32x4*)T;
  const int ldT4 = ldT >> 2;
  f32x4 tpre[4][4];
#pragma unroll
  for (int q = 0; q < 4; ++q) {
    const size_t rbase = (size_t)(prow0 + q * 16 + l15) * ldT4;
#pragma unroll
    for (int p = 0; p < 4; ++p)
      tpre[q][p] = T4[rbase + ((pcol0 + p * 16) >> 2) + lg];
  }
  __builtin_amdgcn_sched_barrier(0);  // don't let the scheduler sink these

  // ---- MFMA phase ----
  f32x4 acc[4][4] = {};  // [p: P-col tile][q: P-row tile]
#pragma unroll
  for (int p = 0; p < 4; ++p)
#pragma unroll
    for (int q = 0; q < 4; ++q)
      acc[p][q] = __builtin_amdgcn_mfma_f32_16x16x32_bf16(y0[p], x0[q], acc[p][q], 0, 0, 0);

#pragma unroll
  for (int kk = 1; kk < 4; ++kk) {
    bf16x8 y[4], x[4];
#pragma unroll
    for (int p = 0; p < 4; ++p)
      y[p] = *(const bf16x8*)(Yrow + (size_t)p * 16 * KDIM + kk * 32);
#pragma unroll
    for (int q = 0; q < 4; ++q)
      x[q] = *(const bf16x8*)(Xrow + (size_t)q * 16 * KDIM + kk * 32);
#pragma unroll
    for (int p = 0; p < 4; ++p)
#pragma unroll
      for (int q = 0; q < 4; ++q)
        acc[p][q] = __builtin_amdgcn_mfma_f32_16x16x32_bf16(y[p], x[q], acc[p][q], 0, 0, 0);
  }

  // ---- epilogue: lane holds P[prow0+q*16+l15][pcol0+p*16+lg*4 .. +3] ----
  float s = 0.f;
#pragma unroll
  for (int q = 0; q < 4; ++q) {
#pragma unroll
    for (int p = 0; p < 4; ++p) {
      const f32x4 tv = tpre[q][p];
      const f32x4 av = acc[p][q];
      const float dx = av[0] - tv[0];
      const float dy = av[1] - tv[1];
      const float dz = av[2] - tv[2];
      const float dw = av[3] - tv[3];
      s += dx * dx + dy * dy + dz * dz + dw * dw;
    }
  }

  // deterministic block reduction
  for (int off = 32; off > 0; off >>= 1) s += __shfl_down(s, off, 64);
  __shared__ float swred[4];
  if (lane == 0) swred[wid] = s;
  __syncthreads();
  if (tid == 0)
    partial[g] = (double)(swred[0] + swred[1] + swred[2] + swred[3]);
}

// Deterministic final reduction of all partial arrays + scalar combine.
__global__ void finalize_kernel(const double* __restrict__ pr, int nr,
                                const double* __restrict__ psm, int nsm,
                                const double* __restrict__ psd, int nsd,
                                const double* __restrict__ pu, int nu,
                                const double* __restrict__ pv, int nv,
                                float* __restrict__ out) {
  __shared__ double sh[256];
  double sums[5];
  const double* ps[5] = {pr, psm, psd, pu, pv};
  int ns[5] = {nr, nsm, nsd, nu, nv};
  for (int q = 0; q < 5; ++q) {
    double s = 0.0;
    for (int i = threadIdx.x; i < ns[q]; i += 256) s += ps[q][i];
    sh[threadIdx.x] = s;
    __syncthreads();
    for (int k = 128; k > 0; k >>= 1) {
      if (threadIdx.x < k) sh[threadIdx.x] += sh[threadIdx.x + k];
      __syncthreads();
    }
    sums[q] = sh[0];
    __syncthreads();
  }
  if (threadIdx.x == 0) {
    double recon = sums[0] / ((double)MDIM * (double)NDIM);
    double res = recon + 0.01 * (sqrt(sums[3]) + sqrt(sums[4]) + sqrt(sums[1]) + sqrt(sums[2]));
    out[0] = (float)res;
  }
}

extern "C" void kernel_launch(void* const* d_in, const int* in_sizes, int n_in,
                              void* d_out, int out_size, void* d_ws, size_t ws_size,
                              hipStream_t stream) {
  const float* A   = (const float*)d_in[0];  // [M][N]
  const float* S_m = (const float*)d_in[1];  // [M][M]
  const float* S_d = (const float*)d_in[2];  // [N][N]
  const float* U   = (const float*)d_in[3];  // [M][K]
  const float* V   = (const float*)d_in[4];  // [N][K]

  char* ws = (char*)d_ws;
  unsigned short* Ub = (unsigned short*)ws;                             // 2 MB
  unsigned short* Vb = (unsigned short*)(ws + (size_t)2 * 1024 * 1024); // 1 MB
  double* pd = (double*)(ws + (size_t)3 * 1024 * 1024);
  double* p_all = pd;            // 7168: [0,2048) recon | [2048,6144) S_m | [6144,7168) S_d
  double* p_u   = p_all + 7168;  // 256
  double* p_v   = p_u + 256;     // 256

  convert_kernel<<<256, 256, 0, stream>>>(U, Ub, p_u, MDIM * KDIM / 4);
  convert_kernel<<<256, 256, 0, stream>>>(V, Vb, p_v, NDIM * KDIM / 4);

  fused_all<<<7168, 256, 0, stream>>>(Ub, Vb, A, S_m, S_d, p_all);

  finalize_kernel<<<1, 256, 0, stream>>>(p_all, 2048, p_all + 2048, 4096, p_all + 6144, 1024,
                                         p_u, 256, p_v, 256, (float*)d_out);
}

// Round 7
// 183.709 us; speedup vs baseline: 1.3832x; 1.0121x over previous
//
#include <hip/hip_runtime.h>
#include <hip/hip_bf16.h>
#include <math.h>

#define MDIM 8192
#define NDIM 4096
#define KDIM 128

typedef __bf16 bf16x8 __attribute__((ext_vector_type(8)));
typedef float f32x4 __attribute__((ext_vector_type(4)));

__device__ __forceinline__ unsigned short f32_to_bf16_rne(float f) {
  unsigned int u = __float_as_uint(f);
  u += 0x7fffu + ((u >> 16) & 1u);
  return (unsigned short)(u >> 16);
}

// Convert f32 -> bf16 (vectorized), and compute sum of squares (for ||U||_F, ||V||_F)
__global__ void convert_kernel(const float* __restrict__ X, unsigned short* __restrict__ Xb,
                               double* __restrict__ partial, int n4) {
  int tid = blockIdx.x * blockDim.x + threadIdx.x;
  int stride = gridDim.x * blockDim.x;
  float s = 0.f;
  const float4* X4 = (const float4*)X;
  ushort4* Xb4 = (ushort4*)Xb;
  for (int i = tid; i < n4; i += stride) {
    float4 v = X4[i];
    s += v.x * v.x + v.y * v.y + v.z * v.z + v.w * v.w;
    ushort4 p;
    p.x = f32_to_bf16_rne(v.x);
    p.y = f32_to_bf16_rne(v.y);
    p.z = f32_to_bf16_rne(v.z);
    p.w = f32_to_bf16_rne(v.w);
    Xb4[i] = p;
  }
  for (int off = 32; off > 0; off >>= 1) s += __shfl_down(s, off, 64);
  __shared__ float sw[4];
  int lane = threadIdx.x & 63, wid = threadIdx.x >> 6;
  if (lane == 0) sw[wid] = s;
  __syncthreads();
  if (threadIdx.x == 0) partial[blockIdx.x] = (double)(sw[0] + sw[1] + sw[2] + sw[3]);
}

// ALL THREE fused products in one dispatch (one 128x128 tile per block):
//   g in [0,2048):      sum((Ub Vb^T - A  )^2)   32 block-cols, ldT=4096
//   g in [2048,6144):   sum((Ub Ub^T - S_m)^2)   64 block-cols, ldT=8192
//   g in [6144,7168):   sum((Vb Vb^T - S_d)^2)   32 block-cols, ldT=4096
//
// R6 diagnosis: vmcnt completes IN ORDER, and kk>=1 fragment loads were
// issued AFTER the 16 T loads -> using them drained the whole T stream from
// HBM mid-kernel. Fix: issue ALL 32 fragment loads first (L2-resident,
// complete early), then the 16 T loads as global_load_lds gathers (no VGPR
// cost; per-lane global addr, linear per-lane LDS slot = register-prefetch
// semantics but in LDS). MFMAs then wait only on frags; the T stream has the
// whole MFMA phase + syncthreads to land. VGPR ~210, 64KB LDS, 2 blocks/CU.
__global__ __launch_bounds__(256, 2) void fused_all(
    const unsigned short* __restrict__ Ub,  // [M][128] bf16 bits
    const unsigned short* __restrict__ Vb,  // [N][128] bf16 bits
    const float* __restrict__ A,            // [M][N]
    const float* __restrict__ S_m,          // [M][M]
    const float* __restrict__ S_d,          // [N][N]
    double* __restrict__ partial) {
  __shared__ float Tlds[16384];  // 64 KB = 16 slots x (256 thr x 16 B)

  const int g = blockIdx.x;

  const unsigned short* Xb;
  const unsigned short* Yb;
  const float* T;
  int ldT, v, gc;
  if (g < 2048) {
    Xb = Ub; Yb = Vb; T = A; ldT = NDIM; v = g; gc = 32;
  } else if (g < 6144) {
    Xb = Ub; Yb = Ub; T = S_m; ldT = MDIM; v = g - 2048; gc = 64;
  } else {
    Xb = Vb; Yb = Vb; T = S_d; ldT = NDIM; v = g - 6144; gc = 32;
  }
  const int r_blk = v / gc;
  const int c_blk = v - r_blk * gc;

  const int tid = threadIdx.x;
  const int lane = tid & 63;
  const int wid = tid >> 6;
  const int wr = wid >> 1, wc = wid & 1;
  const int l15 = lane & 15;
  const int lg = lane >> 4;  // 0..3

  const int prow0 = r_blk * 128 + wr * 64;  // wave's first P-row
  const int pcol0 = c_blk * 128 + wc * 64;  // wave's first P-col

  const unsigned short* Xrow = Xb + (size_t)(prow0 + l15) * KDIM + lg * 8;
  const unsigned short* Yrow = Yb + (size_t)(pcol0 + l15) * KDIM + lg * 8;

  // ---- 1) issue ALL 32 fragment loads (they must precede T in vmcnt order) ----
  bf16x8 y[4][4], x[4][4];  // [kk][tile]
#pragma unroll
  for (int kk = 0; kk < 4; ++kk) {
#pragma unroll
    for (int p = 0; p < 4; ++p)
      y[kk][p] = *(const bf16x8*)(Yrow + (size_t)p * 16 * KDIM + kk * 32);
#pragma unroll
    for (int q = 0; q < 4; ++q)
      x[kk][q] = *(const bf16x8*)(Xrow + (size_t)q * 16 * KDIM + kk * 32);
  }
  __builtin_amdgcn_sched_barrier(0);

  // ---- 2) issue 16 T gathers straight to LDS (fly under the MFMA phase) ----
  const f32x4* T4 = (const f32x4*)T;
  const int ldT4 = ldT >> 2;
#pragma unroll
  for (int q = 0; q < 4; ++q) {
    const size_t rbase = (size_t)(prow0 + q * 16 + l15) * ldT4;
#pragma unroll
    for (int p = 0; p < 4; ++p) {
      const f32x4* gaddr = &T4[rbase + ((pcol0 + p * 16) >> 2) + lg];
      char* laddr = (char*)Tlds + (q * 4 + p) * 4096 + wid * 1024;
      __builtin_amdgcn_global_load_lds(
          (const __attribute__((address_space(1))) void*)gaddr,
          (__attribute__((address_space(3))) void*)laddr, 16, 0, 0);
    }
  }
  __builtin_amdgcn_sched_barrier(0);

  // ---- 3) MFMA phase: waits only on fragment loads ----
  f32x4 acc[4][4] = {};  // [p: P-col tile][q: P-row tile]
#pragma unroll
  for (int kk = 0; kk < 4; ++kk)
#pragma unroll
    for (int p = 0; p < 4; ++p)
#pragma unroll
      for (int q = 0; q < 4; ++q)
        acc[p][q] = __builtin_amdgcn_mfma_f32_16x16x32_bf16(y[kk][p], x[kk][q], acc[p][q], 0, 0, 0);

  // ---- 4) T has landed in LDS by now (syncthreads drains vmcnt) ----
  __syncthreads();

  // ---- 5) epilogue: lane reads back its own 16B slots (conflict-free) ----
  const f32x4* myT = (const f32x4*)((char*)Tlds + wid * 1024 + lane * 16);
  float s = 0.f;
#pragma unroll
  for (int q = 0; q < 4; ++q) {
#pragma unroll
    for (int p = 0; p < 4; ++p) {
      const f32x4 tv = myT[(q * 4 + p) * 256];  // slot stride 4096 B = 256 f32x4
      const f32x4 av = acc[p][q];
      const float dx = av[0] - tv[0];
      const float dy = av[1] - tv[1];
      const float dz = av[2] - tv[2];
      const float dw = av[3] - tv[3];
      s += dx * dx + dy * dy + dz * dz + dw * dw;
    }
  }

  // deterministic block reduction
  for (int off = 32; off > 0; off >>= 1) s += __shfl_down(s, off, 64);
  __shared__ float swred[4];
  if (lane == 0) swred[wid] = s;
  __syncthreads();
  if (tid == 0)
    partial[g] = (double)(swred[0] + swred[1] + swred[2] + swred[3]);
}

// Deterministic final reduction of all partial arrays + scalar combine.
__global__ void finalize_kernel(const double* __restrict__ pr, int nr,
                                const double* __restrict__ psm, int nsm,
                                const double* __restrict__ psd, int nsd,
                                const double* __restrict__ pu, int nu,
                                const double* __restrict__ pv, int nv,
                                float* __restrict__ out) {
  __shared__ double sh[256];
  double sums[5];
  const double* ps[5] = {pr, psm, psd, pu, pv};
  int ns[5] = {nr, nsm, nsd, nu, nv};
  for (int q = 0; q < 5; ++q) {
    double s = 0.0;
    for (int i = threadIdx.x; i < ns[q]; i += 256) s += ps[q][i];
    sh[threadIdx.x] = s;
    __syncthreads();
    for (int k = 128; k > 0; k >>= 1) {
      if (threadIdx.x < k) sh[threadIdx.x] += sh[threadIdx.x + k];
      __syncthreads();
    }
    sums[q] = sh[0];
    __syncthreads();
  }
  if (threadIdx.x == 0) {
    double recon = sums[0] / ((double)MDIM * (double)NDIM);
    double res = recon + 0.01 * (sqrt(sums[3]) + sqrt(sums[4]) + sqrt(sums[1]) + sqrt(sums[2]));
    out[0] = (float)res;
  }
}

extern "C" void kernel_launch(void* const* d_in, const int* in_sizes, int n_in,
                              void* d_out, int out_size, void* d_ws, size_t ws_size,
                              hipStream_t stream) {
  const float* A   = (const float*)d_in[0];  // [M][N]
  const float* S_m = (const float*)d_in[1];  // [M][M]
  const float* S_d = (const float*)d_in[2];  // [N][N]
  const float* U   = (const float*)d_in[3];  // [M][K]
  const float* V   = (const float*)d_in[4];  // [N][K]

  char* ws = (char*)d_ws;
  unsigned short* Ub = (unsigned short*)ws;                             // 2 MB
  unsigned short* Vb = (unsigned short*)(ws + (size_t)2 * 1024 * 1024); // 1 MB
  double* pd = (double*)(ws + (size_t)3 * 1024 * 1024);
  double* p_all = pd;            // 7168: [0,2048) recon | [2048,6144) S_m | [6144,7168) S_d
  double* p_u   = p_all + 7168;  // 256
  double* p_v   = p_u + 256;     // 256

  convert_kernel<<<256, 256, 0, stream>>>(U, Ub, p_u, MDIM * KDIM / 4);
  convert_kernel<<<256, 256, 0, stream>>>(V, Vb, p_v, NDIM * KDIM / 4);

  fused_all<<<7168, 256, 0, stream>>>(Ub, Vb, A, S_m, S_d, p_all);

  finalize_kernel<<<1, 256, 0, stream>>>(p_all, 2048, p_all + 2048, 4096, p_all + 6144, 1024,
                                         p_u, 256, p_v, 256, (float*)d_out);
}